// Round 3
// baseline (949.787 us; speedup 1.0000x reference)
//
#include <hip/hip_runtime.h>
#include <math.h>

// ---- geometry constants (match reference) ----
#define NA   24
#define NU   128
#define NV   64
#define NW   128   // volume W (x)
#define NH   128   // volume H (y)
#define ND   64    // volume D (z)
#define NS   128   // samples per ray
#define F_STEP 1.5625f            // 2*HS/S = 200/128
#define F_DL  (200.0f / 127.0f)   // linspace(156,356,128) spacing
#define F_L0  156.0f
#define INV_DL (127.0f / 200.0f)

#define NRAYS (NA * NV * NU)      // 196608

// Per-ray geometry for FP.
__device__ __forceinline__ void ray_setup(int a, int v, int u,
                                          float& sx, float& sy,
                                          float& dx, float& dy, float& dz) {
    float ang = (float)((double)a * (15.0 * M_PI / 180.0));
    float c = cosf(ang), s = sinf(ang);
    float uu = (float)u - 63.5f;
    float vv = (float)v - 31.5f;
    float ux = 512.0f * c - uu * s;
    float uy = 512.0f * s + uu * c;
    float uz = vv;
    float invn = 1.0f / sqrtf(ux * ux + uy * uy + uz * uz);
    dx = ux * invn; dy = uy * invn; dz = uz * invn;
    sx = -256.0f * c; sy = -256.0f * s;
}

// ---------------- forward projection + residual + cosine weight ----------------
__global__ __launch_bounds__(256) void fp_res_kernel(const float* __restrict__ vol,
                                                     const float* __restrict__ p,
                                                     float* __restrict__ res) {
    int r = blockIdx.x * blockDim.x + threadIdx.x;
    if (r >= NRAYS) return;
    int u = r & (NU - 1);
    int v = (r >> 7) & (NV - 1);
    int a = r >> 13;

    float sx, sy, dx, dy, dz;
    ray_setup(a, v, u, sx, sy, dx, dy, dz);

    float acc = 0.0f;
#pragma unroll 4
    for (int i = 0; i < NS; ++i) {
        float ell = F_L0 + F_DL * (float)i;
        float cx = sx + ell * dx + 63.5f;
        float cy = sy + ell * dy + 63.5f;
        float cz =      ell * dz + 31.5f;
        float fx = floorf(cx), fy = floorf(cy), fz = floorf(cz);
        int ix = (int)fx, iy = (int)fy, iz = (int)fz;
        float wx1 = cx - fx, wy1 = cy - fy, wz1 = cz - fz;
        float wx0 = 1.0f - wx1, wy0 = 1.0f - wy1, wz0 = 1.0f - wz1;
        bool bx0 = (unsigned)ix < NW,      bx1 = (unsigned)(ix + 1) < NW;
        bool by0 = (unsigned)iy < NH,      by1 = (unsigned)(iy + 1) < NH;
        bool bz0 = (unsigned)iz < ND,      bz1 = (unsigned)(iz + 1) < ND;
        long base = ((long)iz * NH + iy) * NW + ix;
        float v000 = (bz0 && by0 && bx0) ? vol[base]                 : 0.0f;
        float v001 = (bz0 && by0 && bx1) ? vol[base + 1]             : 0.0f;
        float v010 = (bz0 && by1 && bx0) ? vol[base + NW]            : 0.0f;
        float v011 = (bz0 && by1 && bx1) ? vol[base + NW + 1]        : 0.0f;
        float v100 = (bz1 && by0 && bx0) ? vol[base + NH * NW]       : 0.0f;
        float v101 = (bz1 && by0 && bx1) ? vol[base + NH * NW + 1]   : 0.0f;
        float v110 = (bz1 && by1 && bx0) ? vol[base + NH * NW + NW]  : 0.0f;
        float v111 = (bz1 && by1 && bx1) ? vol[base + NH * NW + NW + 1] : 0.0f;
        acc += wz0 * (wy0 * (wx0 * v000 + wx1 * v001) +
                      wy1 * (wx0 * v010 + wx1 * v011)) +
               wz1 * (wy0 * (wx0 * v100 + wx1 * v101) +
                      wy1 * (wx0 * v110 + wx1 * v111));
    }
    float sino = acc * F_STEP;
    double du = (double)u - 64.0;
    double dv = (double)v - 32.0;
    float cw = (float)(512.0 / sqrt(512.0 * 512.0 + dv * dv + du * du));
    res[r] = (sino - p[r]) * cw;
}

// ---------------- Ram-Lak ramp filter along u (in place) ----------------
__global__ __launch_bounds__(NU) void ramp_kernel(float* __restrict__ res) {
    __shared__ float row[NU];
    int rowid = blockIdx.x;
    int u = threadIdx.x;
    row[u] = res[rowid * NU + u];
    __syncthreads();
    float acc = 0.125f * row[u];
#pragma unroll
    for (int d = 1; d <= 63; d += 2) {
        float f = (float)(-0.5 / (M_PI * M_PI * (double)(d * d)));
        float lo = (u - d >= 0) ? row[u - d] : 0.0f;
        float hi = (u + d < NU) ? row[u + d] : 0.0f;
        acc += f * (lo + hi);
    }
    res[rowid * NU + u] = acc;
}

// ---------------- back projection: column-wave exact-adjoint gather ----------------
// wave = one (x,y) column, lanes = z. All xy windowing is wave-uniform.
#define BP_THREADS 256
#define BP_CPT     4            // columns per thread (per wave)
#define BP_COLS    16           // columns per block = 4 waves * BP_CPT
#define RES_PITCH  129          // +1 pad: lane-scattered v reads -> 2-way (free)

__global__ __launch_bounds__(BP_THREADS, 4) void bp_gather2(const float* __restrict__ res,
                                                            float* __restrict__ out) {
    __shared__ float s_res[NV * RES_PITCH];           // 33024 B
    __shared__ float s_acc[BP_CPT * BP_THREADS];      // 4096 B (private slots)
    __shared__ float s_trig[NA * 2];

    const int tid  = threadIdx.x;
    const int lane = tid & 63;        // z
    const int wv   = tid >> 6;        // wave 0..3
    if (tid < NA) {
        float ang = (float)((double)tid * (15.0 * M_PI / 180.0));
        s_trig[2 * tid]     = cosf(ang);
        s_trig[2 * tid + 1] = sinf(ang);
    }
#pragma unroll
    for (int cg = 0; cg < BP_CPT; ++cg) s_acc[cg * BP_THREADS + tid] = 0.0f;

    const int x0 = (blockIdx.x & 7) * BP_COLS;   // 8 x-chunks of 16
    const int y  = blockIdx.x >> 3;
    const float y0 = (float)y - 63.5f;
    const float z0 = (float)lane - 31.5f;

    for (int a = 0; a < NA; ++a) {
        __syncthreads();
        // stage res[a] into padded LDS (float4 global loads)
        const float4* rg4 = (const float4*)(res + a * (NV * NU));
#pragma unroll
        for (int k = 0; k < (NV * NU) / (4 * BP_THREADS); ++k) {
            int i4 = tid + k * BP_THREADS;
            float4 t4 = rg4[i4];
            int e = i4 * 4;
            int vv_ = e >> 7, uu_ = e & 127;
            float* dst = &s_res[vv_ * RES_PITCH + uu_];
            dst[0] = t4.x; dst[1] = t4.y; dst[2] = t4.z; dst[3] = t4.w;
        }
        __syncthreads();

        const float c    = s_trig[2 * a];
        const float sn   = s_trig[2 * a + 1];
        const float c512 = 512.0f * c;
        const float s512 = 512.0f * sn;
        const float Vy   = y0 + 256.0f * sn;
        const float ab1  = fabsf(c) + fabsf(sn);

#pragma unroll 1
        for (int cg = 0; cg < BP_CPT; ++cg) {
            const float x0c = (float)(x0 + wv * BP_CPT + cg) - 63.5f;
            const float Vx  = x0c + 256.0f * c;
            const float rho2 = Vx * Vx + Vy * Vy;
            // column t-range (wave-uniform): ell in [min ellc -1.785, max ellc +1.785]
            const float ellc_min = sqrtf(rho2 + 0.25f);
            const float ellc_max = sqrtf(rho2 + 992.25f);
            const float tcol_lo = (ellc_min - 1.785f) * (1.0f / 516.89f);
            const float tcol_hi = (ellc_max + 1.785f) * (1.0f / 512.0f);
            const float inv_tlo = __builtin_amdgcn_rcpf(tcol_lo);
            const float inv_thi = __builtin_amdgcn_rcpf(tcol_hi);
            // u-window (wave-uniform): |t*uu - yp| < |c|+|s|
            const float yp = y0 * c - x0c * sn;
            const float A = yp - ab1, B = yp + ab1;
            const float uu_min = A * ((A >= 0.0f) ? inv_thi : inv_tlo);
            const float uu_max = B * ((B >= 0.0f) ? inv_tlo : inv_thi);
            const int u_lo = max(0,   (int)ceilf(uu_min + 63.49f));
            const int u_hi = min(127, (int)floorf(uu_max + 63.51f));

            float accL = 0.0f;
            if (u_lo <= u_hi) {
#pragma unroll 1
                for (int u = u_lo; u <= u_hi; ++u) {
                    const float uu = (float)u - 63.5f;
                    const float pu = fmaf(-uu, sn, c512);
                    const float qu = fmaf(uu, c, s512);
                    // per-u t-window from x & y slab constraints (wave-uniform)
                    const float rp = __builtin_amdgcn_rcpf(pu);
                    const float rq = __builtin_amdgcn_rcpf(qu);
                    const float ax = (Vx - 1.0f) * rp, bx = (Vx + 1.0f) * rp;
                    const float ay = (Vy - 1.0f) * rq, by = (Vy + 1.0f) * rq;
                    float tl = fmaxf(fminf(ax, bx), fminf(ay, by));
                    float th = fminf(fmaxf(ax, bx), fmaxf(ay, by));
                    tl = fmaxf(tl, tcol_lo);
                    th = fminf(th, tcol_hi);
                    if (tl >= th) continue;            // uniform-valued branch
                    const float rtl = __builtin_amdgcn_rcpf(tl);
                    const float rth = __builtin_amdgcn_rcpf(th);
                    // v-window (per-lane): |t*vv - z0| < 1
                    const float Az = z0 - 1.01f, Bz = z0 + 1.01f;
                    const float vmin = Az * ((Az >= 0.0f) ? rth : rtl);
                    const float vmax = Bz * ((Bz >= 0.0f) ? rtl : rth);
                    const int v_lo = max(0,  (int)ceilf(vmin + 31.49f));
                    const int v_hi = min(63, (int)floorf(vmax + 31.51f));
                    const float c1u = fmaf(uu, uu, 262144.0f);
                    for (int v = v_lo; v <= v_hi; ++v) {
                        const float vv = (float)v - 31.5f;
                        const float rv = s_res[v * RES_PITCH + u];
                        const float arg  = fmaf(vv, vv, c1u);
                        const float invn = rsqrtf(arg);
                        const float nn   = sqrtf(arg);
                        // <=2 candidate i's in the t-window (width < 1.82 in i-units)
                        const float ell_lo = tl * nn;
                        const float i0f  = ceilf(fmaf(ell_lo, INV_DL, -(F_L0 * INV_DL) - 1.0e-3f));
                        const float ell0 = fmaf(i0f, F_DL, F_L0);
                        const float ell1 = ell0 + F_DL;
                        const float t0 = ell0 * invn;
                        const float t1 = ell1 * invn;
                        const float w0x = fmaxf(1.0f - fabsf(fmaf(pu, t0, -Vx)), 0.0f);
                        const float w0y = fmaxf(1.0f - fabsf(fmaf(qu, t0, -Vy)), 0.0f);
                        const float w0z = fmaxf(1.0f - fabsf(fmaf(vv, t0, -z0)), 0.0f);
                        const float w1x = fmaxf(1.0f - fabsf(fmaf(pu, t1, -Vx)), 0.0f);
                        const float w1y = fmaxf(1.0f - fabsf(fmaf(qu, t1, -Vy)), 0.0f);
                        const float w1z = fmaxf(1.0f - fabsf(fmaf(vv, t1, -z0)), 0.0f);
                        const float w = fmaf(w0x * w0y, w0z, w1x * w1y * w1z);
                        accL = fmaf(w, rv, accL);
                    }
                }
            }
            s_acc[cg * BP_THREADS + tid] += accL;   // private slot, no sync needed
        }
    }

    const int xbase = x0 + wv * BP_CPT;
#pragma unroll
    for (int cg = 0; cg < BP_CPT; ++cg) {
        out[(lane << 14) + (y << 7) + xbase + cg] =
            s_acc[cg * BP_THREADS + tid] * F_STEP;   // LAMB = 1
    }
}

extern "C" void kernel_launch(void* const* d_in, const int* in_sizes, int n_in,
                              void* d_out, int out_size, void* d_ws, size_t ws_size,
                              hipStream_t stream) {
    const float* x = (const float*)d_in[0];   // [1,1,64,128,128]
    const float* p = (const float*)d_in[1];   // [1,1,24,64,128]
    float* out = (float*)d_out;               // [1,1,64,128,128]
    float* res = (float*)d_ws;                // NRAYS floats (786 KB)

    fp_res_kernel<<<NRAYS / 256, 256, 0, stream>>>(x, p, res);
    ramp_kernel<<<NA * NV, NU, 0, stream>>>(res);
    bp_gather2<<<(NW * NH) / BP_COLS, BP_THREADS, 0, stream>>>(res, out);
}

// Round 4
// 800.795 us; speedup vs baseline: 1.1861x; 1.1861x over previous
//
#include <hip/hip_runtime.h>
#include <math.h>

// ---- geometry constants (match reference) ----
#define NA   24
#define NU   128
#define NV   64
#define NW   128   // volume W (x)
#define NH   128   // volume H (y)
#define ND   64    // volume D (z)
#define NS   128   // samples per ray
#define F_STEP 1.5625f            // 2*HS/S = 200/128
#define F_DL  (200.0f / 127.0f)   // linspace(156,356,128) spacing
#define F_L0  156.0f
#define INV_DL (127.0f / 200.0f)

#define NRAYS (NA * NV * NU)      // 196608

typedef float v2f __attribute__((ext_vector_type(2)));

// Per-ray geometry for FP.
__device__ __forceinline__ void ray_setup(int a, int v, int u,
                                          float& sx, float& sy,
                                          float& dx, float& dy, float& dz) {
    float ang = (float)((double)a * (15.0 * M_PI / 180.0));
    float c = cosf(ang), s = sinf(ang);
    float uu = (float)u - 63.5f;
    float vv = (float)v - 31.5f;
    float ux = 512.0f * c - uu * s;
    float uy = 512.0f * s + uu * c;
    float uz = vv;
    float invn = 1.0f / sqrtf(ux * ux + uy * uy + uz * uz);
    dx = ux * invn; dy = uy * invn; dz = uz * invn;
    sx = -256.0f * c; sy = -256.0f * s;
}

// ---------------- forward projection, segmented over ell ----------------
// seg = blockIdx.y in {0,1}; writes RAW partial sums (no STEP, no -p, no cw).
__global__ __launch_bounds__(256) void fp_seg_kernel(const float* __restrict__ vol,
                                                     float* __restrict__ part) {
    int r = blockIdx.x * blockDim.x + threadIdx.x;
    int seg = blockIdx.y;
    int u = r & (NU - 1);
    int v = (r >> 7) & (NV - 1);
    int a = r >> 13;

    float sx, sy, dx, dy, dz;
    ray_setup(a, v, u, sx, sy, dx, dy, dz);

    // in-volume ell window (superset; samples outside have all-zero corners)
    float rx = 1.0f / dx, ry = 1.0f / dy, rz = 1.0f / dz;
    float ex0 = (-64.55f - sx) * rx, ex1 = (64.55f - sx) * rx;
    float ey0 = (-64.55f - sy) * ry, ey1 = (64.55f - sy) * ry;
    float ez0 = (-32.55f) * rz,      ez1 = (32.55f) * rz;
    float llo = fmaxf(fmaxf(fminf(ex0, ex1), fminf(ey0, ey1)), fminf(ez0, ez1));
    float lhi = fminf(fminf(fmaxf(ex0, ex1), fmaxf(ey0, ey1)), fmaxf(ez0, ez1));
    int i_lo = max(seg * 64,      (int)ceilf((llo - F_L0) * INV_DL));
    int i_hi = min(seg * 64 + 63, (int)floorf((lhi - F_L0) * INV_DL));

    float acc = 0.0f;
    for (int i = i_lo; i <= i_hi; ++i) {
        float ell = F_L0 + F_DL * (float)i;
        float cx = sx + ell * dx + 63.5f;
        float cy = sy + ell * dy + 63.5f;
        float cz =      ell * dz + 31.5f;
        float fx = floorf(cx), fy = floorf(cy), fz = floorf(cz);
        int ix = (int)fx, iy = (int)fy, iz = (int)fz;
        float wx1 = cx - fx, wy1 = cy - fy, wz1 = cz - fz;
        float wx0 = 1.0f - wx1, wy0 = 1.0f - wy1, wz0 = 1.0f - wz1;
        bool bx0 = (unsigned)ix < NW,      bx1 = (unsigned)(ix + 1) < NW;
        bool by0 = (unsigned)iy < NH,      by1 = (unsigned)(iy + 1) < NH;
        bool bz0 = (unsigned)iz < ND,      bz1 = (unsigned)(iz + 1) < ND;
        long base = ((long)iz * NH + iy) * NW + ix;
        float v000 = (bz0 && by0 && bx0) ? vol[base]                 : 0.0f;
        float v001 = (bz0 && by0 && bx1) ? vol[base + 1]             : 0.0f;
        float v010 = (bz0 && by1 && bx0) ? vol[base + NW]            : 0.0f;
        float v011 = (bz0 && by1 && bx1) ? vol[base + NW + 1]        : 0.0f;
        float v100 = (bz1 && by0 && bx0) ? vol[base + NH * NW]       : 0.0f;
        float v101 = (bz1 && by0 && bx1) ? vol[base + NH * NW + 1]   : 0.0f;
        float v110 = (bz1 && by1 && bx0) ? vol[base + NH * NW + NW]  : 0.0f;
        float v111 = (bz1 && by1 && bx1) ? vol[base + NH * NW + NW + 1] : 0.0f;
        acc += wz0 * (wy0 * (wx0 * v000 + wx1 * v001) +
                      wy1 * (wx0 * v010 + wx1 * v011)) +
               wz1 * (wy0 * (wx0 * v100 + wx1 * v101) +
                      wy1 * (wx0 * v110 + wx1 * v111));
    }
    part[seg * NRAYS + r] = acc;
}

// ---------------- residual + cosine weight + Ram-Lak along u ----------------
__global__ __launch_bounds__(NU) void ramp_kernel(const float* __restrict__ part,
                                                  const float* __restrict__ p,
                                                  float* __restrict__ res) {
    __shared__ float row[NU];
    int rowid = blockIdx.x;          // a*NV + v
    int u = threadIdx.x;
    int e = rowid * NU + u;
    int v = rowid & (NV - 1);
    float sino = (part[e] + part[NRAYS + e]) * F_STEP;
    double du = (double)u - 64.0;
    double dv = (double)v - 32.0;
    float cw = (float)(512.0 / sqrt(262144.0 + dv * dv + du * du));
    row[u] = (sino - p[e]) * cw;
    __syncthreads();
    float acc = 0.125f * row[u];
#pragma unroll
    for (int d = 1; d <= 63; d += 2) {
        float f = (float)(-0.5 / (M_PI * M_PI * (double)(d * d)));
        float lo = (u - d >= 0) ? row[u - d] : 0.0f;
        float hi = (u + d < NU) ? row[u + d] : 0.0f;
        acc += f * (lo + hi);
    }
    res[e] = acc;
}

// ---------------- back projection: scattered-column wave gather ----------------
// Block = 512 threads = 8 waves; wave = column (lanes = z), 2 columns per wave.
// Block b owns columns {b + 1024*j}: x = b&127 fixed, y scattered by 8 -> load balance.
#define RES_PITCH 129

__global__ __launch_bounds__(512, 8) void bp_gather3(const float* __restrict__ res,
                                                     float* __restrict__ out) {
    __shared__ float s_res[NV * RES_PITCH];   // 33024 B
    __shared__ float s_trig[NA * 2];

    const int tid  = threadIdx.x;
    const int lane = tid & 63;        // z
    const int wv   = tid >> 6;        // wave 0..7
    if (tid < NA) {
        float ang = (float)((double)tid * (15.0 * M_PI / 180.0));
        s_trig[2 * tid]     = cosf(ang);
        s_trig[2 * tid + 1] = sinf(ang);
    }

    const int b  = blockIdx.x;
    const int xi = b & 127;
    const int yb = b >> 7;            // 0..7
    const float x0c = (float)xi - 63.5f;
    const float z0  = (float)lane - 31.5f;

    v2f accv0 = {0.0f, 0.0f};
    v2f accv1 = {0.0f, 0.0f};

    for (int a = 0; a < NA; ++a) {
        __syncthreads();
        // conflict-free scalar staging: lane-consecutive u -> 2 lanes/bank (free)
        const float* ra = res + a * (NV * NU);
#pragma unroll
        for (int k = 0; k < 16; ++k) {
            int e = tid + (k << 9);
            s_res[(e >> 7) * RES_PITCH + (e & 127)] = ra[e];
        }
        __syncthreads();

        const float c    = s_trig[2 * a];
        const float sn   = s_trig[2 * a + 1];
        const float c512 = 512.0f * c;
        const float s512 = 512.0f * sn;
        const float Vx   = x0c + 256.0f * c;     // uniform over block (x fixed)
        const float ab1  = fabsf(c) + fabsf(sn);

#pragma unroll
        for (int cg = 0; cg < 2; ++cg) {
            const float y0 = (float)(yb + 8 * wv + 64 * cg) - 63.5f;
            const float Vy = y0 + 256.0f * sn;
            const float rho2 = Vx * Vx + Vy * Vy;
            const float ellc_min = sqrtf(rho2 + 0.25f);
            const float ellc_max = sqrtf(rho2 + 992.25f);
            const float tcol_lo = (ellc_min - 1.785f) * (1.0f / 516.89f);
            const float tcol_hi = (ellc_max + 1.785f) * (1.0f / 512.0f);
            const float inv_tlo = __builtin_amdgcn_rcpf(tcol_lo);
            const float inv_thi = __builtin_amdgcn_rcpf(tcol_hi);
            const float yp = y0 * c - x0c * sn;
            const float A = yp - ab1, B = yp + ab1;
            const float uu_min = A * ((A >= 0.0f) ? inv_thi : inv_tlo);
            const float uu_max = B * ((B >= 0.0f) ? inv_tlo : inv_thi);
            const int u_lo = max(0,   (int)ceilf(uu_min + 63.49f));
            const int u_hi = min(127, (int)floorf(uu_max + 63.51f));

            v2f accv = {0.0f, 0.0f};
#pragma unroll 1
            for (int u = u_lo; u <= u_hi; ++u) {
                const float uu = (float)u - 63.5f;
                const float pu = fmaf(-uu, sn, c512);
                const float qu = fmaf(uu, c, s512);
                const float rp = __builtin_amdgcn_rcpf(pu);
                const float rq = __builtin_amdgcn_rcpf(qu);
                const float ax = (Vx - 1.0f) * rp, bx = (Vx + 1.0f) * rp;
                const float ay = (Vy - 1.0f) * rq, by = (Vy + 1.0f) * rq;
                float tl = fmaxf(fmaxf(fminf(ax, bx), fminf(ay, by)), tcol_lo);
                float th = fminf(fminf(fmaxf(ax, bx), fmaxf(ay, by)), tcol_hi);
                if (tl >= th) continue;            // wave-uniform branch
                const float rtl = __builtin_amdgcn_rcpf(tl);
                const float rth = __builtin_amdgcn_rcpf(th);
                const float Az = z0 - 1.01f, Bz = z0 + 1.01f;
                const float vminf_ = Az * ((Az >= 0.0f) ? rth : rtl);
                const float vmaxf_ = Bz * ((Bz >= 0.0f) ? rtl : rth);
                const int v_lo = max(0,  (int)ceilf(vminf_ + 31.49f));
                const int v_hi = min(63, (int)floorf(vmaxf_ + 31.51f));
                const float c1u = fmaf(uu, uu, 262144.0f);
                for (int v = v_lo; v <= v_hi; ++v) {
                    const float vvf = (float)v - 31.5f;
                    const float arg  = fmaf(vvf, vvf, c1u);
                    const float invn = __builtin_amdgcn_rsqf(arg);
                    const float nn   = arg * invn;        // = sqrt(arg)
                    const float rv   = s_res[v * RES_PITCH + u];
                    const float i0f  = ceilf(fmaf(tl * nn, INV_DL,
                                                  -(F_L0 * INV_DL) - 1.0e-3f));
                    const float ell0 = fmaf(i0f, F_DL, F_L0);
                    v2f ellp; ellp.x = ell0; ellp.y = ell0 + F_DL;
                    const float hx = pu * invn, hy = qu * invn, hz = vvf * invn;
                    v2f hx2 = {hx, hx}, hy2 = {hy, hy}, hz2 = {hz, hz};
                    v2f mx = {-Vx, -Vx}, my = {-Vy, -Vy}, mz = {-z0, -z0};
                    v2f zero2 = {0.0f, 0.0f};
                    v2f wx = __builtin_elementwise_max(
                        1.0f - __builtin_elementwise_abs(__builtin_elementwise_fma(ellp, hx2, mx)), zero2);
                    v2f wy = __builtin_elementwise_max(
                        1.0f - __builtin_elementwise_abs(__builtin_elementwise_fma(ellp, hy2, my)), zero2);
                    v2f wz = __builtin_elementwise_max(
                        1.0f - __builtin_elementwise_abs(__builtin_elementwise_fma(ellp, hz2, mz)), zero2);
                    v2f w = wx * wy * wz;
                    v2f rv2 = {rv, rv};
                    accv = __builtin_elementwise_fma(w, rv2, accv);
                }
            }
            if (cg == 0) accv0 += accv; else accv1 += accv;
        }
    }

    const int y0i = yb + 8 * wv;          // cg = 0
    const int y1i = y0i + 64;             // cg = 1
    out[(lane << 14) + (y0i << 7) + xi] = (accv0.x + accv0.y) * F_STEP;
    out[(lane << 14) + (y1i << 7) + xi] = (accv1.x + accv1.y) * F_STEP;
}

extern "C" void kernel_launch(void* const* d_in, const int* in_sizes, int n_in,
                              void* d_out, int out_size, void* d_ws, size_t ws_size,
                              hipStream_t stream) {
    const float* x = (const float*)d_in[0];   // [1,1,64,128,128]
    const float* p = (const float*)d_in[1];   // [1,1,24,64,128]
    float* out  = (float*)d_out;              // [1,1,64,128,128]
    float* res  = (float*)d_ws;               // filtered residual, NRAYS floats
    float* part = res + NRAYS;                // 2 FP segments, 2*NRAYS floats

    dim3 fpg(NRAYS / 256, 2);
    fp_seg_kernel<<<fpg, 256, 0, stream>>>(x, part);
    ramp_kernel<<<NA * NV, NU, 0, stream>>>(part, p, res);
    bp_gather3<<<(NH * NW) / 16, 512, 0, stream>>>(res, out);
}

// Round 5
// 784.838 us; speedup vs baseline: 1.2102x; 1.0203x over previous
//
#include <hip/hip_runtime.h>
#include <math.h>

// ---- geometry constants (match reference) ----
#define NA   24
#define NU   128
#define NV   64
#define NW   128   // volume W (x)
#define NH   128   // volume H (y)
#define ND   64    // volume D (z)
#define NS   128   // samples per ray
#define F_STEP 1.5625f            // 2*HS/S = 200/128
#define F_DL  (200.0f / 127.0f)   // linspace(156,356,128) spacing
#define F_L0  156.0f
#define INV_DL (127.0f / 200.0f)

#define NRAYS (NA * NV * NU)      // 196608

typedef float v2f __attribute__((ext_vector_type(2)));

// Per-ray geometry for FP.
__device__ __forceinline__ void ray_setup(int a, int v, int u,
                                          float& sx, float& sy,
                                          float& dx, float& dy, float& dz) {
    float ang = (float)((double)a * (15.0 * M_PI / 180.0));
    float c = cosf(ang), s = sinf(ang);
    float uu = (float)u - 63.5f;
    float vv = (float)v - 31.5f;
    float ux = 512.0f * c - uu * s;
    float uy = 512.0f * s + uu * c;
    float uz = vv;
    float invn = 1.0f / sqrtf(ux * ux + uy * uy + uz * uz);
    dx = ux * invn; dy = uy * invn; dz = uz * invn;
    sx = -256.0f * c; sy = -256.0f * s;
}

// ---------------- forward projection, segmented over ell ----------------
__global__ __launch_bounds__(256) void fp_seg_kernel(const float* __restrict__ vol,
                                                     float* __restrict__ part) {
    int r = blockIdx.x * blockDim.x + threadIdx.x;
    int seg = blockIdx.y;
    int u = r & (NU - 1);
    int v = (r >> 7) & (NV - 1);
    int a = r >> 13;

    float sx, sy, dx, dy, dz;
    ray_setup(a, v, u, sx, sy, dx, dy, dz);

    // in-volume ell window (superset; samples outside have all-zero corners)
    float rx = 1.0f / dx, ry = 1.0f / dy, rz = 1.0f / dz;
    float ex0 = (-64.55f - sx) * rx, ex1 = (64.55f - sx) * rx;
    float ey0 = (-64.55f - sy) * ry, ey1 = (64.55f - sy) * ry;
    float ez0 = (-32.55f) * rz,      ez1 = (32.55f) * rz;
    float llo = fmaxf(fmaxf(fminf(ex0, ex1), fminf(ey0, ey1)), fminf(ez0, ez1));
    float lhi = fminf(fminf(fmaxf(ex0, ex1), fmaxf(ey0, ey1)), fmaxf(ez0, ez1));
    int i_lo = max(seg * 64,      (int)ceilf((llo - F_L0) * INV_DL));
    int i_hi = min(seg * 64 + 63, (int)floorf((lhi - F_L0) * INV_DL));

    float acc = 0.0f;
    for (int i = i_lo; i <= i_hi; ++i) {
        float ell = F_L0 + F_DL * (float)i;
        float cx = sx + ell * dx + 63.5f;
        float cy = sy + ell * dy + 63.5f;
        float cz =      ell * dz + 31.5f;
        float fx = floorf(cx), fy = floorf(cy), fz = floorf(cz);
        int ix = (int)fx, iy = (int)fy, iz = (int)fz;
        float wx1 = cx - fx, wy1 = cy - fy, wz1 = cz - fz;
        float wx0 = 1.0f - wx1, wy0 = 1.0f - wy1, wz0 = 1.0f - wz1;
        bool bx0 = (unsigned)ix < NW,      bx1 = (unsigned)(ix + 1) < NW;
        bool by0 = (unsigned)iy < NH,      by1 = (unsigned)(iy + 1) < NH;
        bool bz0 = (unsigned)iz < ND,      bz1 = (unsigned)(iz + 1) < ND;
        long base = ((long)iz * NH + iy) * NW + ix;
        float v000 = (bz0 && by0 && bx0) ? vol[base]                 : 0.0f;
        float v001 = (bz0 && by0 && bx1) ? vol[base + 1]             : 0.0f;
        float v010 = (bz0 && by1 && bx0) ? vol[base + NW]            : 0.0f;
        float v011 = (bz0 && by1 && bx1) ? vol[base + NW + 1]        : 0.0f;
        float v100 = (bz1 && by0 && bx0) ? vol[base + NH * NW]       : 0.0f;
        float v101 = (bz1 && by0 && bx1) ? vol[base + NH * NW + 1]   : 0.0f;
        float v110 = (bz1 && by1 && bx0) ? vol[base + NH * NW + NW]  : 0.0f;
        float v111 = (bz1 && by1 && bx1) ? vol[base + NH * NW + NW + 1] : 0.0f;
        acc += wz0 * (wy0 * (wx0 * v000 + wx1 * v001) +
                      wy1 * (wx0 * v010 + wx1 * v011)) +
               wz1 * (wy0 * (wx0 * v100 + wx1 * v101) +
                      wy1 * (wx0 * v110 + wx1 * v111));
    }
    part[seg * NRAYS + r] = acc;
}

// ---------------- residual + cosine weight + Ram-Lak along u ----------------
__global__ __launch_bounds__(NU) void ramp_kernel(const float* __restrict__ part,
                                                  const float* __restrict__ p,
                                                  float* __restrict__ res) {
    __shared__ float row[NU];
    int rowid = blockIdx.x;          // a*NV + v
    int u = threadIdx.x;
    int e = rowid * NU + u;
    int v = rowid & (NV - 1);
    float sino = (part[e] + part[NRAYS + e]) * F_STEP;
    double du = (double)u - 64.0;
    double dv = (double)v - 32.0;
    float cw = (float)(512.0 / sqrt(262144.0 + dv * dv + du * du));
    row[u] = (sino - p[e]) * cw;
    __syncthreads();
    float acc = 0.125f * row[u];
#pragma unroll
    for (int d = 1; d <= 63; d += 2) {
        float f = (float)(-0.5 / (M_PI * M_PI * (double)(d * d)));
        float lo = (u - d >= 0) ? row[u - d] : 0.0f;
        float hi = (u + d < NU) ? row[u + d] : 0.0f;
        acc += f * (lo + hi);
    }
    res[e] = acc;
}

// ---------------- back projection: thread-per-voxel gather, lanes = x ----------------
// Block = 512 threads = 4 (y,z)-rows of 128 x. Every lane owns a voxel ->
// no structurally-empty lanes (the lanes=z version idled ~50% of lanes).
// Rows scattered in (y,z) for balance: y=(yb+32r)&127, z=zb+16r (bijective).
#define RES_PITCH 129

__global__ __launch_bounds__(512, 8) void bp_gather4(const float* __restrict__ res,
                                                     float* __restrict__ out) {
    __shared__ float s_res[NV * RES_PITCH];   // 33024 B

    const int tid = threadIdx.x;
    const int xi  = tid & 127;
    const int rr  = tid >> 7;          // row 0..3
    const int yb  = blockIdx.x & 127;
    const int zb  = blockIdx.x >> 7;   // 0..15
    const int yi  = (yb + 32 * rr) & 127;
    const int zi  = zb + 16 * rr;

    const float x0 = (float)xi - 63.5f;
    const float y0 = (float)yi - 63.5f;
    const float z0 = (float)zi - 31.5f;
    const float Az = z0 - 1.01f, Bz = z0 + 1.01f;
    const bool  sAz = (Az >= 0.0f), sBz = (Bz >= 0.0f);
    const float zz2 = z0 * z0;

    v2f acc = {0.0f, 0.0f};

    for (int a = 0; a < NA; ++a) {
        __syncthreads();
        // stage res[a]: lane-consecutive u -> 2 lanes/bank (free); coalesced global
        const float* ra = res + a * (NV * NU);
#pragma unroll
        for (int k = 0; k < 16; ++k) {
            int e = tid + (k << 9);
            s_res[(e >> 7) * RES_PITCH + (e & 127)] = ra[e];
        }
        __syncthreads();

        float ang = (float)((double)a * (15.0 * M_PI / 180.0));
        const float c  = cosf(ang);
        const float sn = sinf(ang);
        const float c512 = 512.0f * c;
        const float s512 = 512.0f * sn;
        const float ab1  = fabsf(c) + fabsf(sn);

        const float Vx  = x0 + 256.0f * c;
        const float Vy  = y0 + 256.0f * sn;
        const float Vxm = Vx - 1.0f, Vxp = Vx + 1.0f;
        const float Vym = Vy - 1.0f, Vyp = Vy + 1.0f;
        const float ellc = sqrtf(fmaf(Vx, Vx, fmaf(Vy, Vy, zz2)));
        const float tvlo = (ellc - 1.785f) * (1.0f / 517.0f);
        const float tvhi = (ellc + 1.785f) * (1.0f / 512.0f);
        const float itlo = __builtin_amdgcn_rcpf(tvlo);
        const float ithi = __builtin_amdgcn_rcpf(tvhi);
        const float yp = y0 * c - x0 * sn;
        const float A = yp - ab1, B = yp + ab1;
        const float uumin = A * ((A >= 0.0f) ? ithi : itlo);
        const float uumax = B * ((B >= 0.0f) ? itlo : ithi);
        const int u_lo = max(0,   (int)ceilf(uumin + 63.49f));
        const int u_hi = min(127, (int)floorf(uumax + 63.51f));

        float uuf = (float)u_lo - 63.5f;
        for (int u = u_lo; u <= u_hi; ++u, uuf += 1.0f) {
            const float pu = fmaf(-uuf, sn, c512);
            const float qu = fmaf(uuf, c, s512);
            const float rp = __builtin_amdgcn_rcpf(pu);
            const float rq = __builtin_amdgcn_rcpf(qu);
            const float ax = Vxm * rp, bx = Vxp * rp;
            const float ay = Vym * rq, by = Vyp * rq;
            const float tl = fmaxf(fmaxf(fminf(ax, bx), fminf(ay, by)), tvlo);
            const float th = fminf(fminf(fmaxf(ax, bx), fmaxf(ay, by)), tvhi);
            if (tl < th) {                       // divergent; exec-masked
                const float rtl = __builtin_amdgcn_rcpf(tl);
                const float rth = __builtin_amdgcn_rcpf(th);
                const float vminf_ = Az * (sAz ? rth : rtl);
                const float vmaxf_ = Bz * (sBz ? rtl : rth);
                const int v_lo = max(0,  (int)ceilf(vminf_ + 31.49f));
                const int v_hi = min(63, (int)floorf(vmaxf_ + 31.51f));
                const float c1u  = fmaf(uuf, uuf, 262144.0f);
                const float tlDL = tl * INV_DL;
                float vvf = (float)v_lo - 31.5f;
                for (int v = v_lo; v <= v_hi; ++v, vvf += 1.0f) {
                    const float arg  = fmaf(vvf, vvf, c1u);
                    const float invn = __builtin_amdgcn_rsqf(arg);
                    const float nn   = arg * invn;        // sqrt(arg)
                    const float rv   = s_res[v * RES_PITCH + u];
                    // <=2 candidate ell grid points in [tl*nn, th*nn]
                    const float i0f  = ceilf(fmaf(tlDL, nn,
                                                  -(F_L0 * INV_DL) - 1.0e-3f));
                    const float ell0 = fmaf(i0f, F_DL, F_L0);
                    v2f tp;
                    tp.x = ell0 * invn;
                    tp.y = fmaf(F_DL, invn, tp.x);
                    const v2f pu2 = {pu, pu}, qu2 = {qu, qu}, vv2 = {vvf, vvf};
                    const v2f mVx = {-Vx, -Vx}, mVy = {-Vy, -Vy}, mz0 = {-z0, -z0};
                    const v2f one2 = {1.0f, 1.0f}, zero2 = {0.0f, 0.0f};
                    v2f wx = __builtin_elementwise_max(
                        one2 - __builtin_elementwise_abs(__builtin_elementwise_fma(tp, pu2, mVx)), zero2);
                    v2f wy = __builtin_elementwise_max(
                        one2 - __builtin_elementwise_abs(__builtin_elementwise_fma(tp, qu2, mVy)), zero2);
                    v2f wz = __builtin_elementwise_max(
                        one2 - __builtin_elementwise_abs(__builtin_elementwise_fma(tp, vv2, mz0)), zero2);
                    const v2f w = wx * wy * wz;
                    const v2f rv2 = {rv, rv};
                    acc = __builtin_elementwise_fma(w, rv2, acc);
                }
            }
        }
    }

    out[(zi << 14) + (yi << 7) + xi] = (acc.x + acc.y) * F_STEP;   // LAMB = 1
}

extern "C" void kernel_launch(void* const* d_in, const int* in_sizes, int n_in,
                              void* d_out, int out_size, void* d_ws, size_t ws_size,
                              hipStream_t stream) {
    const float* x = (const float*)d_in[0];   // [1,1,64,128,128]
    const float* p = (const float*)d_in[1];   // [1,1,24,64,128]
    float* out  = (float*)d_out;              // [1,1,64,128,128]
    float* res  = (float*)d_ws;               // filtered residual, NRAYS floats
    float* part = res + NRAYS;                // 2 FP segments, 2*NRAYS floats

    dim3 fpg(NRAYS / 256, 2);
    fp_seg_kernel<<<fpg, 256, 0, stream>>>(x, part);
    ramp_kernel<<<NA * NV, NU, 0, stream>>>(part, p, res);
    bp_gather4<<<(NW * NH * ND) / 512, 512, 0, stream>>>(res, out);
}